// Round 13
// baseline (305.700 us; speedup 1.0000x reference)
//
#include <hip/hip_runtime.h>
#include <cmath>

#define CC 64
#define HH 512
#define WWID 512
#define HWSZ (HH*WWID)
#define DEPTH 4

typedef __attribute__((ext_vector_type(8))) short short8;
typedef __attribute__((ext_vector_type(4))) float floatx4;

__device__ inline unsigned short f2bf(float f){
  unsigned int u = __float_as_uint(f);
  u += 0x7FFF + ((u >> 16) & 1);          // round-to-nearest-even
  return (unsigned short)(u >> 16);
}
__device__ inline float bf2f(unsigned short h){
  return __uint_as_float(((unsigned int)h) << 16);
}

// ---------------- init (+ zero Xf for layer-0 dftw atomics) ----------------
__global__ void k_init(const float* __restrict__ ww,
                       float* __restrict__ ctab, float* __restrict__ stab,
                       unsigned short* __restrict__ trigBh, unsigned short* __restrict__ trigBl,
                       unsigned short* __restrict__ trigTh, unsigned short* __restrict__ trigTl,
                       unsigned short* __restrict__ Whi, unsigned short* __restrict__ Wlo,
                       float4* __restrict__ Xfz){
  if (blockIdx.x < 32) Xfz[blockIdx.x*256 + threadIdx.x] = make_float4(0.f,0.f,0.f,0.f);
  int idx = blockIdx.x*256 + threadIdx.x;
  if (idx < 8192){
    int pos = idx >> 4, k = idx & 15;
    int r = (pos * k) & 511;
    double ang = (2.0 * 3.14159265358979323846 / 512.0) * (double)r;
    float c = (float)cos(ang), s = (float)sin(ang);
    ctab[idx] = c;  stab[idx] = s;
    unsigned short ch = f2bf(c), sh = f2bf(s);
    unsigned short cl = f2bf(c - bf2f(ch)), sl = f2bf(s - bf2f(sh));
    trigBh[pos*32 + 2*k]     = ch;  trigBl[pos*32 + 2*k]     = cl;
    trigBh[pos*32 + 2*k + 1] = sh;  trigBl[pos*32 + 2*k + 1] = sl;
    trigTh[(2*k)*512 + pos]   = ch;  trigTl[(2*k)*512 + pos]   = cl;
    trigTh[(2*k+1)*512 + pos] = sh;  trigTl[(2*k+1)*512 + pos] = sl;
  } else {
    int t = idx - 8192;                   // < 4*64*64, flat [d][o][i]
    float v = ww[t];
    unsigned short h = f2bf(v);
    Whi[t] = h;  Wlo[t] = f2bf(v - bf2f(h));
  }
}

// ---------------- A+B1 fused: DFT along w (MFMA) -> LDS -> h-partial DFT -> atomicAdd Xf ----------------
// Block b: channel i = b>>3, h range [64*(b&7), +64). LIFT=1: read q + on-the-fly lift (layer 0).
// Hybrid staging: A (x data, zero intra-block reuse) loads DIRECT from global per-lane;
// B (trig, 4x wave reuse x 16 reads) staged WHOLE (64 KB) in LDS once, one barrier.
// LDS = 75008 B -> 2 blocks/CU.
#define XPITCH 33
#define BPITCH 520
template<int LIFT>
__global__ __launch_bounds__(256) void k_dftw(const unsigned int* __restrict__ xp,
    const float* __restrict__ qsrc, const float* __restrict__ pw, const float* __restrict__ pb,
    const unsigned short* __restrict__ trigTh, const unsigned short* __restrict__ trigTl,
    const float* __restrict__ ctab, const float* __restrict__ stab,
    float* __restrict__ Xfa, float4* __restrict__ Yz){
  if (blockIdx.x < 32) Yz[blockIdx.x*256 + threadIdx.x] = make_float4(0.f,0.f,0.f,0.f);

  __shared__ unsigned short Bhs[32*BPITCH], Bls[32*BPITCH];
  __shared__ float X1s[64*XPITCH];            // [hh][j]: j=2n -> Re, 2n+1 -> Im
  int row0 = blockIdx.x * 64;                 // rows = i*512 + h
  int i  = row0 >> 9;
  int h0 = row0 & 511;
  int t = threadIdx.x;
  int g = t >> 6, lm = t & 15, lq = (t >> 4) & 3;
  float pa = 0.f, pbv = 0.f;
  if (LIFT){ pa = pw[i]; pbv = pb[i]; }       // block-uniform scalars

  {   // stage whole trig table: 2048 b128 chunks per array, coalesced
    #pragma unroll
    for (int u = 0; u < 8; ++u){
      int idx = u*256 + t;                    // 0..2047
      int row = idx >> 6, ck = (idx & 63)*8;
      *(uint4*)&Bhs[row*BPITCH + ck] = *(const uint4*)(trigTh + row*512 + ck);
      *(uint4*)&Bls[row*BPITCH + ck] = *(const uint4*)(trigTl + row*512 + ck);
    }
  }
  __syncthreads();

  floatx4 acc[2] = {{0.f,0.f,0.f,0.f},{0.f,0.f,0.f,0.f}};

  int hrow = h0 + g*16 + lm;                  // this lane's A row (h)
  const unsigned int* arow = xp + ((size_t)hrow*64 + i)*512;
  const float*        qrow = qsrc + (size_t)hrow*512;

  #pragma unroll 4
  for (int ch = 0; ch < 16; ++ch){            // K chunks of 32 w; lane k-offset lq*8
    int kb = ch*32 + lq*8;
    short8 ah, al;
    if (LIFT){                                // fp32 q + lift + split (layer 0 only)
      float4 qa = *(const float4*)(qrow + kb);
      float4 qb = *(const float4*)(qrow + kb + 4);
      float v[8] = {qa.x,qa.y,qa.z,qa.w,qb.x,qb.y,qb.z,qb.w};
      unsigned int hs[4], ls[4];
      #pragma unroll
      for (int p = 0; p < 4; ++p){
        float v0 = fmaf(pa, v[2*p],   pbv);
        float v1 = fmaf(pa, v[2*p+1], pbv);
        unsigned short hh0 = f2bf(v0), hh1 = f2bf(v1);
        unsigned short gg0 = f2bf(v0 - bf2f(hh0)), gg1 = f2bf(v1 - bf2f(hh1));
        hs[p] = (unsigned)hh0 | ((unsigned)hh1 << 16);
        ls[p] = (unsigned)gg0 | ((unsigned)gg1 << 16);
      }
      ah = *(short8*)hs;  al = *(short8*)ls;
    } else {                                  // packed x: pure unpack, no conversion
      uint4 va = *(const uint4*)(arow + kb);
      uint4 vb = *(const uint4*)(arow + kb + 4);
      unsigned int u[8] = {va.x,va.y,va.z,va.w,vb.x,vb.y,vb.z,vb.w};
      unsigned int hs[4], ls[4];
      #pragma unroll
      for (int p = 0; p < 4; ++p){
        hs[p] = (u[2*p] & 0xffffu) | (u[2*p+1] << 16);
        ls[p] = (u[2*p] >> 16)     | (u[2*p+1] & 0xffff0000u);
      }
      ah = *(short8*)hs;  al = *(short8*)ls;
    }
    #pragma unroll
    for (int nt = 0; nt < 2; ++nt){
      int j = nt*16 + lm;                     // B row (trig col) from LDS
      short8 bh = *(const short8*)&Bhs[j*BPITCH + kb];
      short8 bl = *(const short8*)&Bls[j*BPITCH + kb];
      acc[nt] = __builtin_amdgcn_mfma_f32_16x16x32_bf16(ah, bh, acc[nt], 0, 0, 0);
      acc[nt] = __builtin_amdgcn_mfma_f32_16x16x32_bf16(ah, bl, acc[nt], 0, 0, 0);
      acc[nt] = __builtin_amdgcn_mfma_f32_16x16x32_bf16(al, bh, acc[nt], 0, 0, 0);
    }
  }

  // D -> LDS (sign-folded): row hh = g*16+lq*4+rg, col j = nt*16+lm; odd j negated
  __syncthreads();                            // all ds_reads of Bhs done before X1s overlap era
  #pragma unroll
  for (int nt = 0; nt < 2; ++nt){
    int j = nt*16 + lm;
    float sgn = (j & 1) ? -1.f : 1.f;
    #pragma unroll
    for (int rg = 0; rg < 4; ++rg){
      int m = g*16 + lq*4 + rg;
      X1s[m*XPITCH + j] = sgn * acc[nt][rg];
    }
  }
  __syncthreads();

  // h-partial DFT: thread (mo,n) sums its 64 h's, atomicAdd into Xf[i][mn]
  int mo = t >> 4, n = t & 15;
  float ar = 0.f, ai = 0.f;
  #pragma unroll 8
  for (int hh = 0; hh < 64; ++hh){
    int h = h0 + hh;
    float Re = X1s[hh*XPITCH + 2*n];
    float Im = X1s[hh*XPITCH + 2*n + 1];
    float c = ctab[h*16 + mo], s = stab[h*16 + mo];
    ar += Re*c + Im*s;
    ai += Im*c - Re*s;
  }
  atomicAdd(&Xfa[(i*256 + t)*2],     ar);
  atomicAdd(&Xfa[(i*256 + t)*2 + 1], ai);
}

// ---------------- B2: mode contraction, i-chunked, mn-split; atomicAdd into Y ----------------
__global__ void k_contract(const float2* __restrict__ Xf,
                           const float* __restrict__ wr, const float* __restrict__ wi,
                           float* __restrict__ Ya){
  int o = blockIdx.x, ic = blockIdx.y;
  int mn = blockIdx.z*64 + threadIdx.x;
  float ar = 0.f, ai = 0.f;
  int i0 = ic * 16;
  #pragma unroll
  for (int ii = 0; ii < 16; ++ii){
    int i = i0 + ii;
    float2 xf = Xf[i*256 + mn];
    float wrv = wr[(i*64 + o)*256 + mn];
    float wiv = wi[(i*64 + o)*256 + mn];
    ar += xf.x*wrv - xf.y*wiv;
    ai += xf.x*wiv + xf.y*wrv;
  }
  const float sc = 1.f/262144.f;
  atomicAdd(&Ya[(o*256 + mn)*2],     ar*sc);
  atomicAdd(&Ya[(o*256 + mn)*2 + 1], ai*sc);
}

// ---------------- B3: iDFT along h -> T split bf16; zero-Xf tail (next layer's accumulator) ----------------
__global__ void k_idfth(const float2* __restrict__ Y, const float* __restrict__ ct,
                        const float* __restrict__ st,
                        unsigned int* __restrict__ Thi, unsigned int* __restrict__ Tlo,
                        float4* __restrict__ Xfz){
  if (blockIdx.x < 32) Xfz[blockIdx.x*256 + threadIdx.x] = make_float4(0.f,0.f,0.f,0.f);
  int idx = blockIdx.x*256 + threadIdx.x;     // (h*64+o)*16+n
  int n = idx & 15, o = (idx >> 4) & 63, h = idx >> 10;
  float ar = 0.f, ai = 0.f;
  #pragma unroll
  for (int m = 0; m < 16; ++m){
    float2 y = Y[(o<<8) + (m<<4) + n];
    float c = ct[h*16 + m], s = st[h*16 + m];
    ar += y.x*c - y.y*s;
    ai += y.x*s + y.y*c;
  }
  float tr = ar, ts = -ai;
  unsigned short rh = f2bf(tr), sh = f2bf(ts);
  Thi[idx] = (unsigned int)rh | ((unsigned int)sh << 16);   // [2n]=Tr low, [2n+1]=-Ti high
  unsigned short rl = f2bf(tr - bf2f(rh)), slr = f2bf(ts - bf2f(sh));
  Tlo[idx] = (unsigned int)rl | ((unsigned int)slr << 16);
}

// ---------------- C: combine GEMM (K=96), split-bf16 3-pass, 64o x 128w tiles ----------------
// R13: B-fragment GLOBAL LOADS hoisted ABOVE the A-staging barrier — their L2/HBM latency
// overlaps the staging stores + barrier drain instead of sitting on the post-barrier
// critical path (compiler can't hoist loads across s_barrier itself). Unpack stays after
// the barrier; MFMA order unchanged -> bit-identical results.
#define PITCH 104
template<int LIFT, int FINAL>
__global__ __launch_bounds__(256) void k_combine(
    const unsigned int* __restrict__ xp, const float* __restrict__ qsrc,
    const float* __restrict__ pw, const float* __restrict__ pb,
    const unsigned short* __restrict__ Whid, const unsigned short* __restrict__ Wlod,
    const unsigned int* __restrict__ Thi,  const unsigned int* __restrict__ Tlo,
    const unsigned short* __restrict__ trigBh, const unsigned short* __restrict__ trigBl,
    const float* __restrict__ wb, unsigned int* __restrict__ xo,
    const float* __restrict__ fw, const float* __restrict__ fb,
    float* __restrict__ outp)
{
  __shared__ unsigned short Ah[64*PITCH], Al[64*PITCH];     // rows o, k 0..95
  int h  = blockIdx.y;
  int w0 = blockIdx.x * 128;
  int t  = threadIdx.x;

  int g  = t >> 6;          // wave -> w-subtile: pixels [w0+32g, +32)
  int lm = t & 15;
  int lq = (t >> 4) & 3;
  int wbase = w0 + g*32;

  const unsigned int* xw = xp + (size_t)h*32768;   // [h][i][w] slab

  // ---- ISSUE all B-fragment global loads FIRST (latency hides under A staging) ----
  unsigned int v0[2][8], v1[2][8];
  short8 tbh[2], tbl[2];
  if (LIFT){
    float pwv[16], pbv[16];
    #pragma unroll
    for (int u = 0; u < 8; ++u){
      pwv[u]   = pw[lq*8 + u];      pbv[u]   = pb[lq*8 + u];
      pwv[8+u] = pw[32 + lq*8 + u]; pbv[8+u] = pb[32 + lq*8 + u];
    }
    #pragma unroll
    for (int nt = 0; nt < 2; ++nt){
      int w = wbase + nt*16 + lm;
      float qv = qsrc[(size_t)h*512 + w];
      #pragma unroll
      for (int u = 0; u < 8; ++u){
        float a = fmaf(pwv[u], qv, pbv[u]);
        unsigned short hh = f2bf(a), ll = f2bf(a - bf2f(hh));
        v0[nt][u] = (unsigned int)hh | ((unsigned int)ll << 16);
        float b = fmaf(pwv[8+u], qv, pbv[8+u]);
        unsigned short hb = f2bf(b), lb = f2bf(b - bf2f(hb));
        v1[nt][u] = (unsigned int)hb | ((unsigned int)lb << 16);
      }
      tbh[nt] = *(const short8*)(trigBh + (size_t)w*32 + lq*8);
      tbl[nt] = *(const short8*)(trigBl + (size_t)w*32 + lq*8);
    }
  } else {
    #pragma unroll
    for (int nt = 0; nt < 2; ++nt){
      int w = wbase + nt*16 + lm;
      #pragma unroll
      for (int u = 0; u < 8; ++u){
        v0[nt][u] = xw[(size_t)(     lq*8 + u)*512 + w];
        v1[nt][u] = xw[(size_t)(32 + lq*8 + u)*512 + w];
      }
      tbh[nt] = *(const short8*)(trigBh + (size_t)w*32 + lq*8);
      tbl[nt] = *(const short8*)(trigBl + (size_t)w*32 + lq*8);
    }
  }

  {   // A W-part: rows o, k=0..63 (b128 copies)
    int o = t >> 2, q8 = t & 3;
    const uint4* sh = (const uint4*)((const unsigned int*)Whid + o*32 + q8*8);
    const uint4* sl = (const uint4*)((const unsigned int*)Wlod + o*32 + q8*8);
    uint4* dh = (uint4*)((unsigned int*)&Ah[o*PITCH] + q8*8);
    uint4* dl = (uint4*)((unsigned int*)&Al[o*PITCH] + q8*8);
    dh[0] = sh[0]; dh[1] = sh[1];
    dl[0] = sl[0]; dl[1] = sl[1];
  }
  {   // A T-part: rows o, k=64..95 (b128 copies)
    int o = t >> 2, q4 = t & 3;
    const uint4* sh = (const uint4*)(Thi + (size_t)h*1024 + o*16 + q4*4);
    const uint4* sl = (const uint4*)(Tlo + (size_t)h*1024 + o*16 + q4*4);
    uint4* dh = (uint4*)((unsigned int*)&Ah[o*PITCH + 64] + q4*4);
    uint4* dl = (uint4*)((unsigned int*)&Al[o*PITCH + 64] + q4*4);
    dh[0] = sh[0];
    dl[0] = sl[0];
  }
  __syncthreads();

  // ---- unpack B fragments (registers only; loads already landed) ----
  short8 bf0[2], bl0[2], bf1[2], bl1[2], bf2[2], bl2[2];
  #pragma unroll
  for (int nt = 0; nt < 2; ++nt){
    unsigned int f0[4], l0[4], f1[4], l1[4];
    #pragma unroll
    for (int p = 0; p < 4; ++p){
      f0[p] = (v0[nt][2*p] & 0xffffu) | (v0[nt][2*p+1] << 16);
      l0[p] = (v0[nt][2*p] >> 16)     | (v0[nt][2*p+1] & 0xffff0000u);
      f1[p] = (v1[nt][2*p] & 0xffffu) | (v1[nt][2*p+1] << 16);
      l1[p] = (v1[nt][2*p] >> 16)     | (v1[nt][2*p+1] & 0xffff0000u);
    }
    bf0[nt] = *(short8*)f0;  bl0[nt] = *(short8*)l0;
    bf1[nt] = *(short8*)f1;  bl1[nt] = *(short8*)l1;
    bf2[nt] = tbh[nt];
    bl2[nt] = tbl[nt];
  }

  floatx4 acc[8] = {{0.f,0.f,0.f,0.f},{0.f,0.f,0.f,0.f},{0.f,0.f,0.f,0.f},{0.f,0.f,0.f,0.f},
                    {0.f,0.f,0.f,0.f},{0.f,0.f,0.f,0.f},{0.f,0.f,0.f,0.f},{0.f,0.f,0.f,0.f}};

  // ---- m-tile loop: A via ds_read, reused by both n-tiles ----
  #pragma unroll
  for (int m = 0; m < 4; ++m){
    short8 af0 = *(const short8*)&Ah[(m*16 + lm)*PITCH +  0 + lq*8];
    short8 al0 = *(const short8*)&Al[(m*16 + lm)*PITCH +  0 + lq*8];
    short8 af1 = *(const short8*)&Ah[(m*16 + lm)*PITCH + 32 + lq*8];
    short8 al1 = *(const short8*)&Al[(m*16 + lm)*PITCH + 32 + lq*8];
    short8 af2 = *(const short8*)&Ah[(m*16 + lm)*PITCH + 64 + lq*8];
    short8 al2 = *(const short8*)&Al[(m*16 + lm)*PITCH + 64 + lq*8];
    #pragma unroll
    for (int nt = 0; nt < 2; ++nt){
      int a = m*2 + nt;
      acc[a] = __builtin_amdgcn_mfma_f32_16x16x32_bf16(af0, bf0[nt], acc[a], 0, 0, 0);
      acc[a] = __builtin_amdgcn_mfma_f32_16x16x32_bf16(af0, bl0[nt], acc[a], 0, 0, 0);
      acc[a] = __builtin_amdgcn_mfma_f32_16x16x32_bf16(al0, bf0[nt], acc[a], 0, 0, 0);
      acc[a] = __builtin_amdgcn_mfma_f32_16x16x32_bf16(af1, bf1[nt], acc[a], 0, 0, 0);
      acc[a] = __builtin_amdgcn_mfma_f32_16x16x32_bf16(af1, bl1[nt], acc[a], 0, 0, 0);
      acc[a] = __builtin_amdgcn_mfma_f32_16x16x32_bf16(al1, bf1[nt], acc[a], 0, 0, 0);
      acc[a] = __builtin_amdgcn_mfma_f32_16x16x32_bf16(af2, bf2[nt], acc[a], 0, 0, 0);
      acc[a] = __builtin_amdgcn_mfma_f32_16x16x32_bf16(af2, bl2[nt], acc[a], 0, 0, 0);
      acc[a] = __builtin_amdgcn_mfma_f32_16x16x32_bf16(al2, bf2[nt], acc[a], 0, 0, 0);
    }
  }

  if (!FINAL){
    // epilogue: bias + tanh-gelu + packed split-bf16 store into [h][i][w]
    #pragma unroll
    for (int m = 0; m < 4; ++m){
      #pragma unroll
      for (int nt = 0; nt < 2; ++nt){
        int w = wbase + nt*16 + lm;
        #pragma unroll
        for (int rg = 0; rg < 4; ++rg){
          int o = m*16 + lq*4 + rg;
          float u = acc[m*2+nt][rg] + wb[o];
          float z = 0.7978845608028654f * fmaf(0.044715f, u*u*u, u);
          float e = __expf(2.f*z);
          float gl = u - __fdividef(u, e + 1.f);
          unsigned short hi_ = f2bf(gl);
          unsigned short lo_ = f2bf(gl - bf2f(hi_));
          xo[((size_t)h*64 + o)*512 + w] = (unsigned int)hi_ | ((unsigned int)lo_ << 16);
        }
      }
    }
  } else {
    // epilogue: bias + gelu + final projection reduced in-block (fuses k_final).
    // fred aliases Ah; barrier orders vs all waves' ds_reads of A.
    float* fred = (float*)Ah;                 // 128*17*4 = 8704 B <= 13312 B
    __syncthreads();
    #pragma unroll
    for (int nt = 0; nt < 2; ++nt){
      float partial = 0.f;
      #pragma unroll
      for (int m = 0; m < 4; ++m){
        #pragma unroll
        for (int rg = 0; rg < 4; ++rg){
          int o = m*16 + lq*4 + rg;
          float u = acc[m*2+nt][rg] + wb[o];
          float z = 0.7978845608028654f * fmaf(0.044715f, u*u*u, u);
          float e = __expf(2.f*z);
          float gl = u - __fdividef(u, e + 1.f);
          partial = fmaf(fw[o], gl, partial);
        }
      }
      int wl = g*32 + nt*16 + lm;             // 0..127 within the block's w-tile
      fred[wl*17 + lq] = partial;
    }
    __syncthreads();
    if (t < 128){
      float s = fb[0];
      #pragma unroll
      for (int k2 = 0; k2 < 4; ++k2) s += fred[t*17 + k2];
      outp[(size_t)h*512 + w0 + t] = s;
    }
  }
}

extern "C" void kernel_launch(void* const* d_in, const int* in_sizes, int n_in,
                              void* d_out, int out_size, void* d_ws, size_t ws_size,
                              hipStream_t stream) {
  const float* q       = (const float*)d_in[0];
  const float* proj_w  = (const float*)d_in[1];
  const float* proj_b  = (const float*)d_in[2];
  const float* spec_wr = (const float*)d_in[3];
  const float* spec_wi = (const float*)d_in[4];
  const float* w_w     = (const float*)d_in[5];
  const float* w_b     = (const float*)d_in[6];
  const float* final_w = (const float*)d_in[7];
  const float* final_b = (const float*)d_in[8];
  float* out = (float*)d_out;

  // Workspace (bytes, end-exclusive) — unchanged layout; x region packed uint32 [h][i][w]:
  //   ctab   [       0,   32768)
  //   stab   [   32768,   65536)
  //   trigBh [   65536,   98304)   trigBl [   98304,  131072)
  //   Thi    [  131072,  2228224)  Tlo [ 2228224,  4325376)
  //   Xf     [ 4325376,  4456448)  128 KiB (dftw atomics; zeroed by init/idfth tails)
  //   Y      [ 4456448,  4587520)  128 KiB (contract atomics; zeroed by dftw tail)
  //   x      [ 4587520, 71696384)  64 MiB packed split-bf16 [h][i][w]
  //   Whi    [71696384, 71729152)  Wlo [71729152, 71761920)
  //   trigTh [71761920, 71794688)  trigTl [71794688, 71827456)   total ~68.5 MiB
  char* ws = (char*)d_ws;
  float*  ctab = (float*) (ws + 0);
  float*  stab = (float*) (ws + 32768);
  unsigned short* trigBh = (unsigned short*)(ws + 65536);
  unsigned short* trigBl = (unsigned short*)(ws + 98304);
  unsigned int* Thi = (unsigned int*)(ws + 131072);
  unsigned int* Tlo = (unsigned int*)(ws + 2228224);
  float*  Xf   = (float*) (ws + 4325376);
  float*  Y    = (float*) (ws + 4456448);
  unsigned int* x = (unsigned int*)(ws + 4587520);
  unsigned short* Whi = (unsigned short*)(ws + 71696384);
  unsigned short* Wlo = (unsigned short*)(ws + 71729152);
  unsigned short* trigTh = (unsigned short*)(ws + 71761920);
  unsigned short* trigTl = (unsigned short*)(ws + 71794688);

  k_init<<<96, 256, 0, stream>>>(w_w, ctab, stab, trigBh, trigBl, trigTh, trigTl,
                                 Whi, Wlo, (float4*)Xf);

  for (int d = 0; d < DEPTH; ++d){
    if (d == 0)
      k_dftw<1><<<512, 256, 0, stream>>>(x, q, proj_w, proj_b, trigTh, trigTl,
                                         ctab, stab, Xf, (float4*)Y);
    else
      k_dftw<0><<<512, 256, 0, stream>>>(x, q, proj_w, proj_b, trigTh, trigTl,
                                         ctab, stab, Xf, (float4*)Y);
    k_contract<<<dim3(64,4,4), 64, 0, stream>>>((const float2*)Xf,
                                                spec_wr + (size_t)d*1048576,
                                                spec_wi + (size_t)d*1048576, Y);
    k_idfth<<<2048, 256, 0, stream>>>((const float2*)Y, ctab, stab, Thi, Tlo,
                                      (float4*)Xf);
    if (d == 0)
      k_combine<1,0><<<dim3(4,512), 256, 0, stream>>>(x, q, proj_w, proj_b,
          Whi + d*4096, Wlo + d*4096, Thi, Tlo, trigBh, trigBl,
          w_b + d*64, x, final_w, final_b, out);
    else if (d < DEPTH-1)
      k_combine<0,0><<<dim3(4,512), 256, 0, stream>>>(x, q, proj_w, proj_b,
          Whi + d*4096, Wlo + d*4096, Thi, Tlo, trigBh, trigBl,
          w_b + d*64, x, final_w, final_b, out);
    else
      k_combine<0,1><<<dim3(4,512), 256, 0, stream>>>(x, q, proj_w, proj_b,
          Whi + d*4096, Wlo + d*4096, Thi, Tlo, trigBh, trigBl,
          w_b + d*64, x, final_w, final_b, out);
  }
}

// Round 14
// 301.964 us; speedup vs baseline: 1.0124x; 1.0124x over previous
//
#include <hip/hip_runtime.h>
#include <cmath>

#define CC 64
#define HH 512
#define WWID 512
#define HWSZ (HH*WWID)
#define DEPTH 4

typedef __attribute__((ext_vector_type(8))) short short8;
typedef __attribute__((ext_vector_type(4))) float floatx4;

__device__ inline unsigned short f2bf(float f){
  unsigned int u = __float_as_uint(f);
  u += 0x7FFF + ((u >> 16) & 1);          // round-to-nearest-even
  return (unsigned short)(u >> 16);
}
__device__ inline float bf2f(unsigned short h){
  return __uint_as_float(((unsigned int)h) << 16);
}

// ---------------- init (+ zero Xf for layer-0 dftw atomics) ----------------
__global__ void k_init(const float* __restrict__ ww,
                       float* __restrict__ ctab, float* __restrict__ stab,
                       unsigned short* __restrict__ trigBh, unsigned short* __restrict__ trigBl,
                       unsigned short* __restrict__ trigTh, unsigned short* __restrict__ trigTl,
                       unsigned short* __restrict__ Whi, unsigned short* __restrict__ Wlo,
                       float4* __restrict__ Xfz){
  if (blockIdx.x < 32) Xfz[blockIdx.x*256 + threadIdx.x] = make_float4(0.f,0.f,0.f,0.f);
  int idx = blockIdx.x*256 + threadIdx.x;
  if (idx < 8192){
    int pos = idx >> 4, k = idx & 15;
    int r = (pos * k) & 511;
    double ang = (2.0 * 3.14159265358979323846 / 512.0) * (double)r;
    float c = (float)cos(ang), s = (float)sin(ang);
    ctab[idx] = c;  stab[idx] = s;
    unsigned short ch = f2bf(c), sh = f2bf(s);
    unsigned short cl = f2bf(c - bf2f(ch)), sl = f2bf(s - bf2f(sh));
    trigBh[pos*32 + 2*k]     = ch;  trigBl[pos*32 + 2*k]     = cl;
    trigBh[pos*32 + 2*k + 1] = sh;  trigBl[pos*32 + 2*k + 1] = sl;
    trigTh[(2*k)*512 + pos]   = ch;  trigTl[(2*k)*512 + pos]   = cl;
    trigTh[(2*k+1)*512 + pos] = sh;  trigTl[(2*k+1)*512 + pos] = sl;
  } else {
    int t = idx - 8192;                   // < 4*64*64, flat [d][o][i]
    float v = ww[t];
    unsigned short h = f2bf(v);
    Whi[t] = h;  Wlo[t] = f2bf(v - bf2f(h));
  }
}

// ---------------- A+B1 fused: DFT along w (MFMA) -> LDS -> h-partial DFT -> atomicAdd Xf ----------------
// Block b: channel i = b>>3, h range [64*(b&7), +64). LIFT=1: read q + on-the-fly lift (layer 0).
// Hybrid staging (R7 post-mortem): A (x data, zero intra-block reuse) loads DIRECT from
// global per-lane; B (trig, 4x wave reuse x 16 reads) staged WHOLE (64 KB) in LDS once,
// one barrier. BPITCH=520 -> ds_read bank stride 4*lm%32 = 2-way aliasing (free).
// LDS = 66560+8448 = 75008 B -> 2 blocks/CU.
#define XPITCH 33
#define BPITCH 520
template<int LIFT>
__global__ __launch_bounds__(256) void k_dftw(const unsigned int* __restrict__ xp,
    const float* __restrict__ qsrc, const float* __restrict__ pw, const float* __restrict__ pb,
    const unsigned short* __restrict__ trigTh, const unsigned short* __restrict__ trigTl,
    const float* __restrict__ ctab, const float* __restrict__ stab,
    float* __restrict__ Xfa, float4* __restrict__ Yz){
  if (blockIdx.x < 32) Yz[blockIdx.x*256 + threadIdx.x] = make_float4(0.f,0.f,0.f,0.f);

  __shared__ unsigned short Bhs[32*BPITCH], Bls[32*BPITCH];
  __shared__ float X1s[64*XPITCH];            // [hh][j]: j=2n -> Re, 2n+1 -> Im
  int row0 = blockIdx.x * 64;                 // rows = i*512 + h
  int i  = row0 >> 9;
  int h0 = row0 & 511;
  int t = threadIdx.x;
  int g = t >> 6, lm = t & 15, lq = (t >> 4) & 3;
  float pa = 0.f, pbv = 0.f;
  if (LIFT){ pa = pw[i]; pbv = pb[i]; }       // block-uniform scalars

  {   // stage whole trig table: 2048 b128 chunks per array, coalesced (consecutive t -> consecutive 16B)
    #pragma unroll
    for (int u = 0; u < 8; ++u){
      int idx = u*256 + t;                    // 0..2047
      int row = idx >> 6, ck = (idx & 63)*8;
      *(uint4*)&Bhs[row*BPITCH + ck] = *(const uint4*)(trigTh + row*512 + ck);
      *(uint4*)&Bls[row*BPITCH + ck] = *(const uint4*)(trigTl + row*512 + ck);
    }
  }
  __syncthreads();

  floatx4 acc[2] = {{0.f,0.f,0.f,0.f},{0.f,0.f,0.f,0.f}};

  int hrow = h0 + g*16 + lm;                  // this lane's A row (h)
  const unsigned int* arow = xp + ((size_t)hrow*64 + i)*512;
  const float*        qrow = qsrc + (size_t)hrow*512;

  #pragma unroll 4
  for (int ch = 0; ch < 16; ++ch){            // K chunks of 32 w; lane k-offset lq*8
    int kb = ch*32 + lq*8;
    short8 ah, al;
    if (LIFT){                                // fp32 q + lift + split (layer 0 only)
      float4 qa = *(const float4*)(qrow + kb);
      float4 qb = *(const float4*)(qrow + kb + 4);
      float v[8] = {qa.x,qa.y,qa.z,qa.w,qb.x,qb.y,qb.z,qb.w};
      unsigned int hs[4], ls[4];
      #pragma unroll
      for (int p = 0; p < 4; ++p){
        float v0 = fmaf(pa, v[2*p],   pbv);
        float v1 = fmaf(pa, v[2*p+1], pbv);
        unsigned short hh0 = f2bf(v0), hh1 = f2bf(v1);
        unsigned short gg0 = f2bf(v0 - bf2f(hh0)), gg1 = f2bf(v1 - bf2f(hh1));
        hs[p] = (unsigned)hh0 | ((unsigned)hh1 << 16);
        ls[p] = (unsigned)gg0 | ((unsigned)gg1 << 16);
      }
      ah = *(short8*)hs;  al = *(short8*)ls;
    } else {                                  // packed x: pure unpack, no conversion
      uint4 va = *(const uint4*)(arow + kb);
      uint4 vb = *(const uint4*)(arow + kb + 4);
      unsigned int u[8] = {va.x,va.y,va.z,va.w,vb.x,vb.y,vb.z,vb.w};
      unsigned int hs[4], ls[4];
      #pragma unroll
      for (int p = 0; p < 4; ++p){
        hs[p] = (u[2*p] & 0xffffu) | (u[2*p+1] << 16);
        ls[p] = (u[2*p] >> 16)     | (u[2*p+1] & 0xffff0000u);
      }
      ah = *(short8*)hs;  al = *(short8*)ls;
    }
    #pragma unroll
    for (int nt = 0; nt < 2; ++nt){
      int j = nt*16 + lm;                     // B row (trig col) from LDS
      short8 bh = *(const short8*)&Bhs[j*BPITCH + kb];
      short8 bl = *(const short8*)&Bls[j*BPITCH + kb];
      acc[nt] = __builtin_amdgcn_mfma_f32_16x16x32_bf16(ah, bh, acc[nt], 0, 0, 0);
      acc[nt] = __builtin_amdgcn_mfma_f32_16x16x32_bf16(ah, bl, acc[nt], 0, 0, 0);
      acc[nt] = __builtin_amdgcn_mfma_f32_16x16x32_bf16(al, bh, acc[nt], 0, 0, 0);
    }
  }

  // D -> LDS (sign-folded): row hh = g*16+lq*4+rg, col j = nt*16+lm; odd j negated
  __syncthreads();                            // all ds_reads of Bhs done before X1s overlap era
  #pragma unroll
  for (int nt = 0; nt < 2; ++nt){
    int j = nt*16 + lm;
    float sgn = (j & 1) ? -1.f : 1.f;
    #pragma unroll
    for (int rg = 0; rg < 4; ++rg){
      int m = g*16 + lq*4 + rg;
      X1s[m*XPITCH + j] = sgn * acc[nt][rg];
    }
  }
  __syncthreads();

  // h-partial DFT: thread (mo,n) sums its 64 h's, atomicAdd into Xf[i][mn]
  int mo = t >> 4, n = t & 15;
  float ar = 0.f, ai = 0.f;
  #pragma unroll 8
  for (int hh = 0; hh < 64; ++hh){
    int h = h0 + hh;
    float Re = X1s[hh*XPITCH + 2*n];
    float Im = X1s[hh*XPITCH + 2*n + 1];
    float c = ctab[h*16 + mo], s = stab[h*16 + mo];
    ar += Re*c + Im*s;
    ai += Im*c - Re*s;
  }
  atomicAdd(&Xfa[(i*256 + t)*2],     ar);
  atomicAdd(&Xfa[(i*256 + t)*2 + 1], ai);
}

// ---------------- B2: mode contraction, i-chunked, mn-split; atomicAdd into Y ----------------
__global__ void k_contract(const float2* __restrict__ Xf,
                           const float* __restrict__ wr, const float* __restrict__ wi,
                           float* __restrict__ Ya){
  int o = blockIdx.x, ic = blockIdx.y;
  int mn = blockIdx.z*64 + threadIdx.x;
  float ar = 0.f, ai = 0.f;
  int i0 = ic * 16;
  #pragma unroll
  for (int ii = 0; ii < 16; ++ii){
    int i = i0 + ii;
    float2 xf = Xf[i*256 + mn];
    float wrv = wr[(i*64 + o)*256 + mn];
    float wiv = wi[(i*64 + o)*256 + mn];
    ar += xf.x*wrv - xf.y*wiv;
    ai += xf.x*wiv + xf.y*wrv;
  }
  const float sc = 1.f/262144.f;
  atomicAdd(&Ya[(o*256 + mn)*2],     ar*sc);
  atomicAdd(&Ya[(o*256 + mn)*2 + 1], ai*sc);
}

// ---------------- B3: iDFT along h -> T split bf16; zero-Xf tail (next layer's accumulator) ----------------
__global__ void k_idfth(const float2* __restrict__ Y, const float* __restrict__ ct,
                        const float* __restrict__ st,
                        unsigned int* __restrict__ Thi, unsigned int* __restrict__ Tlo,
                        float4* __restrict__ Xfz){
  if (blockIdx.x < 32) Xfz[blockIdx.x*256 + threadIdx.x] = make_float4(0.f,0.f,0.f,0.f);
  int idx = blockIdx.x*256 + threadIdx.x;     // (h*64+o)*16+n
  int n = idx & 15, o = (idx >> 4) & 63, h = idx >> 10;
  float ar = 0.f, ai = 0.f;
  #pragma unroll
  for (int m = 0; m < 16; ++m){
    float2 y = Y[(o<<8) + (m<<4) + n];
    float c = ct[h*16 + m], s = st[h*16 + m];
    ar += y.x*c - y.y*s;
    ai += y.x*s + y.y*c;
  }
  float tr = ar, ts = -ai;
  unsigned short rh = f2bf(tr), sh = f2bf(ts);
  Thi[idx] = (unsigned int)rh | ((unsigned int)sh << 16);   // [2n]=Tr low, [2n+1]=-Ti high
  unsigned short rl = f2bf(tr - bf2f(rh)), slr = f2bf(ts - bf2f(sh));
  Tlo[idx] = (unsigned int)rl | ((unsigned int)slr << 16);
}

// ---------------- C: combine GEMM (K=96), split-bf16 3-pass, 64o x 128w tiles ----------------
// Waves partition w (wave g owns 32 pixels), not o: B fragments are loaded ONCE per block
// (no 4x inter-wave redundancy; 32 dword loads/thread, all batched). A (64 o-rows x 96 k)
// sits in LDS (26.6 KB) and is ds_read per 16-row m-tile (PITCH 104 -> 2-way = free).
// Same 72 MFMAs/thread in the same per-acc order -> bit-identical results.
#define PITCH 104
template<int LIFT, int FINAL>
__global__ __launch_bounds__(256) void k_combine(
    const unsigned int* __restrict__ xp, const float* __restrict__ qsrc,
    const float* __restrict__ pw, const float* __restrict__ pb,
    const unsigned short* __restrict__ Whid, const unsigned short* __restrict__ Wlod,
    const unsigned int* __restrict__ Thi,  const unsigned int* __restrict__ Tlo,
    const unsigned short* __restrict__ trigBh, const unsigned short* __restrict__ trigBl,
    const float* __restrict__ wb, unsigned int* __restrict__ xo,
    const float* __restrict__ fw, const float* __restrict__ fb,
    float* __restrict__ outp)
{
  __shared__ unsigned short Ah[64*PITCH], Al[64*PITCH];     // rows o, k 0..95
  int h  = blockIdx.y;
  int w0 = blockIdx.x * 128;
  int t  = threadIdx.x;

  {   // A W-part: rows o, k=0..63 (b128 copies)
    int o = t >> 2, q8 = t & 3;
    const uint4* sh = (const uint4*)((const unsigned int*)Whid + o*32 + q8*8);
    const uint4* sl = (const uint4*)((const unsigned int*)Wlod + o*32 + q8*8);
    uint4* dh = (uint4*)((unsigned int*)&Ah[o*PITCH] + q8*8);
    uint4* dl = (uint4*)((unsigned int*)&Al[o*PITCH] + q8*8);
    dh[0] = sh[0]; dh[1] = sh[1];
    dl[0] = sl[0]; dl[1] = sl[1];
  }
  {   // A T-part: rows o, k=64..95 (b128 copies)
    int o = t >> 2, q4 = t & 3;
    const uint4* sh = (const uint4*)(Thi + (size_t)h*1024 + o*16 + q4*4);
    const uint4* sl = (const uint4*)(Tlo + (size_t)h*1024 + o*16 + q4*4);
    uint4* dh = (uint4*)((unsigned int*)&Ah[o*PITCH + 64] + q4*4);
    uint4* dl = (uint4*)((unsigned int*)&Al[o*PITCH + 64] + q4*4);
    dh[0] = sh[0];
    dl[0] = sl[0];
  }
  __syncthreads();

  int g  = t >> 6;          // wave -> w-subtile: pixels [w0+32g, +32)
  int lm = t & 15;
  int lq = (t >> 4) & 3;
  int wbase = w0 + g*32;

  const unsigned int* xw = xp + (size_t)h*32768;   // [h][i][w] slab
  float pwv[16], pbv[16];
  if (LIFT){
    #pragma unroll
    for (int u = 0; u < 8; ++u){
      pwv[u]   = pw[lq*8 + u];      pbv[u]   = pb[lq*8 + u];
      pwv[8+u] = pw[32 + lq*8 + u]; pbv[8+u] = pb[32 + lq*8 + u];
    }
  }

  // ---- load ALL B fragments for this wave's 2 n-tiles up front (batched) ----
  short8 bf0[2], bl0[2], bf1[2], bl1[2], bf2[2], bl2[2];
  #pragma unroll
  for (int nt = 0; nt < 2; ++nt){
    int w = wbase + nt*16 + lm;
    unsigned int v0[8], v1[8];
    if (LIFT){
      float qv = qsrc[(size_t)h*512 + w];
      #pragma unroll
      for (int u = 0; u < 8; ++u){
        float a = fmaf(pwv[u], qv, pbv[u]);
        unsigned short hh = f2bf(a), ll = f2bf(a - bf2f(hh));
        v0[u] = (unsigned int)hh | ((unsigned int)ll << 16);
        float b = fmaf(pwv[8+u], qv, pbv[8+u]);
        unsigned short hb = f2bf(b), lb = f2bf(b - bf2f(hb));
        v1[u] = (unsigned int)hb | ((unsigned int)lb << 16);
      }
    } else {
      #pragma unroll
      for (int u = 0; u < 8; ++u){
        v0[u] = xw[(size_t)(     lq*8 + u)*512 + w];
        v1[u] = xw[(size_t)(32 + lq*8 + u)*512 + w];
      }
    }
    unsigned int f0[4], l0[4], f1[4], l1[4];
    #pragma unroll
    for (int p = 0; p < 4; ++p){
      f0[p] = (v0[2*p] & 0xffffu) | (v0[2*p+1] << 16);
      l0[p] = (v0[2*p] >> 16)     | (v0[2*p+1] & 0xffff0000u);
      f1[p] = (v1[2*p] & 0xffffu) | (v1[2*p+1] << 16);
      l1[p] = (v1[2*p] >> 16)     | (v1[2*p+1] & 0xffff0000u);
    }
    bf0[nt] = *(short8*)f0;  bl0[nt] = *(short8*)l0;
    bf1[nt] = *(short8*)f1;  bl1[nt] = *(short8*)l1;
    bf2[nt] = *(const short8*)(trigBh + (size_t)w*32 + lq*8);
    bl2[nt] = *(const short8*)(trigBl + (size_t)w*32 + lq*8);
  }

  floatx4 acc[8] = {{0.f,0.f,0.f,0.f},{0.f,0.f,0.f,0.f},{0.f,0.f,0.f,0.f},{0.f,0.f,0.f,0.f},
                    {0.f,0.f,0.f,0.f},{0.f,0.f,0.f,0.f},{0.f,0.f,0.f,0.f},{0.f,0.f,0.f,0.f}};

  // ---- m-tile loop: A via ds_read, reused by both n-tiles ----
  #pragma unroll
  for (int m = 0; m < 4; ++m){
    short8 af0 = *(const short8*)&Ah[(m*16 + lm)*PITCH +  0 + lq*8];
    short8 al0 = *(const short8*)&Al[(m*16 + lm)*PITCH +  0 + lq*8];
    short8 af1 = *(const short8*)&Ah[(m*16 + lm)*PITCH + 32 + lq*8];
    short8 al1 = *(const short8*)&Al[(m*16 + lm)*PITCH + 32 + lq*8];
    short8 af2 = *(const short8*)&Ah[(m*16 + lm)*PITCH + 64 + lq*8];
    short8 al2 = *(const short8*)&Al[(m*16 + lm)*PITCH + 64 + lq*8];
    #pragma unroll
    for (int nt = 0; nt < 2; ++nt){
      int a = m*2 + nt;
      acc[a] = __builtin_amdgcn_mfma_f32_16x16x32_bf16(af0, bf0[nt], acc[a], 0, 0, 0);
      acc[a] = __builtin_amdgcn_mfma_f32_16x16x32_bf16(af0, bl0[nt], acc[a], 0, 0, 0);
      acc[a] = __builtin_amdgcn_mfma_f32_16x16x32_bf16(al0, bf0[nt], acc[a], 0, 0, 0);
      acc[a] = __builtin_amdgcn_mfma_f32_16x16x32_bf16(af1, bf1[nt], acc[a], 0, 0, 0);
      acc[a] = __builtin_amdgcn_mfma_f32_16x16x32_bf16(af1, bl1[nt], acc[a], 0, 0, 0);
      acc[a] = __builtin_amdgcn_mfma_f32_16x16x32_bf16(al1, bf1[nt], acc[a], 0, 0, 0);
      acc[a] = __builtin_amdgcn_mfma_f32_16x16x32_bf16(af2, bf2[nt], acc[a], 0, 0, 0);
      acc[a] = __builtin_amdgcn_mfma_f32_16x16x32_bf16(af2, bl2[nt], acc[a], 0, 0, 0);
      acc[a] = __builtin_amdgcn_mfma_f32_16x16x32_bf16(al2, bf2[nt], acc[a], 0, 0, 0);
    }
  }

  if (!FINAL){
    // epilogue: bias + tanh-gelu + packed split-bf16 store into [h][i][w]
    #pragma unroll
    for (int m = 0; m < 4; ++m){
      #pragma unroll
      for (int nt = 0; nt < 2; ++nt){
        int w = wbase + nt*16 + lm;
        #pragma unroll
        for (int rg = 0; rg < 4; ++rg){
          int o = m*16 + lq*4 + rg;
          float u = acc[m*2+nt][rg] + wb[o];
          float z = 0.7978845608028654f * fmaf(0.044715f, u*u*u, u);
          float e = __expf(2.f*z);
          float gl = u - __fdividef(u, e + 1.f);
          unsigned short hi_ = f2bf(gl);
          unsigned short lo_ = f2bf(gl - bf2f(hi_));
          xo[((size_t)h*64 + o)*512 + w] = (unsigned int)hi_ | ((unsigned int)lo_ << 16);
        }
      }
    }
  } else {
    // epilogue: bias + gelu + final projection reduced in-block (fuses k_final).
    // fred aliases Ah; barrier orders vs all waves' ds_reads of A.
    float* fred = (float*)Ah;                 // 128*17*4 = 8704 B <= 13312 B
    __syncthreads();
    #pragma unroll
    for (int nt = 0; nt < 2; ++nt){
      float partial = 0.f;
      #pragma unroll
      for (int m = 0; m < 4; ++m){
        #pragma unroll
        for (int rg = 0; rg < 4; ++rg){
          int o = m*16 + lq*4 + rg;
          float u = acc[m*2+nt][rg] + wb[o];
          float z = 0.7978845608028654f * fmaf(0.044715f, u*u*u, u);
          float e = __expf(2.f*z);
          float gl = u - __fdividef(u, e + 1.f);
          partial = fmaf(fw[o], gl, partial);
        }
      }
      int wl = g*32 + nt*16 + lm;             // 0..127 within the block's w-tile
      fred[wl*17 + lq] = partial;
    }
    __syncthreads();
    if (t < 128){
      float s = fb[0];
      #pragma unroll
      for (int k2 = 0; k2 < 4; ++k2) s += fred[t*17 + k2];
      outp[(size_t)h*512 + w0 + t] = s;
    }
  }
}

extern "C" void kernel_launch(void* const* d_in, const int* in_sizes, int n_in,
                              void* d_out, int out_size, void* d_ws, size_t ws_size,
                              hipStream_t stream) {
  const float* q       = (const float*)d_in[0];
  const float* proj_w  = (const float*)d_in[1];
  const float* proj_b  = (const float*)d_in[2];
  const float* spec_wr = (const float*)d_in[3];
  const float* spec_wi = (const float*)d_in[4];
  const float* w_w     = (const float*)d_in[5];
  const float* w_b     = (const float*)d_in[6];
  const float* final_w = (const float*)d_in[7];
  const float* final_b = (const float*)d_in[8];
  float* out = (float*)d_out;

  // Workspace (bytes, end-exclusive) — x region packed uint32 [h][i][w]:
  //   ctab   [       0,   32768)
  //   stab   [   32768,   65536)
  //   trigBh [   65536,   98304)   trigBl [   98304,  131072)
  //   Thi    [  131072,  2228224)  Tlo [ 2228224,  4325376)
  //   Xf     [ 4325376,  4456448)  128 KiB (dftw atomics; zeroed by init/idfth tails)
  //   Y      [ 4456448,  4587520)  128 KiB (contract atomics; zeroed by dftw tail)
  //   x      [ 4587520, 71696384)  64 MiB packed split-bf16 [h][i][w]
  //   Whi    [71696384, 71729152)  Wlo [71729152, 71761920)
  //   trigTh [71761920, 71794688)  trigTl [71794688, 71827456)   total ~68.5 MiB
  char* ws = (char*)d_ws;
  float*  ctab = (float*) (ws + 0);
  float*  stab = (float*) (ws + 32768);
  unsigned short* trigBh = (unsigned short*)(ws + 65536);
  unsigned short* trigBl = (unsigned short*)(ws + 98304);
  unsigned int* Thi = (unsigned int*)(ws + 131072);
  unsigned int* Tlo = (unsigned int*)(ws + 2228224);
  float*  Xf   = (float*) (ws + 4325376);
  float*  Y    = (float*) (ws + 4456448);
  unsigned int* x = (unsigned int*)(ws + 4587520);
  unsigned short* Whi = (unsigned short*)(ws + 71696384);
  unsigned short* Wlo = (unsigned short*)(ws + 71729152);
  unsigned short* trigTh = (unsigned short*)(ws + 71761920);
  unsigned short* trigTl = (unsigned short*)(ws + 71794688);

  k_init<<<96, 256, 0, stream>>>(w_w, ctab, stab, trigBh, trigBl, trigTh, trigTl,
                                 Whi, Wlo, (float4*)Xf);

  for (int d = 0; d < DEPTH; ++d){
    if (d == 0)
      k_dftw<1><<<512, 256, 0, stream>>>(x, q, proj_w, proj_b, trigTh, trigTl,
                                         ctab, stab, Xf, (float4*)Y);
    else
      k_dftw<0><<<512, 256, 0, stream>>>(x, q, proj_w, proj_b, trigTh, trigTl,
                                         ctab, stab, Xf, (float4*)Y);
    k_contract<<<dim3(64,4,4), 64, 0, stream>>>((const float2*)Xf,
                                                spec_wr + (size_t)d*1048576,
                                                spec_wi + (size_t)d*1048576, Y);
    k_idfth<<<2048, 256, 0, stream>>>((const float2*)Y, ctab, stab, Thi, Tlo,
                                      (float4*)Xf);
    if (d == 0)
      k_combine<1,0><<<dim3(4,512), 256, 0, stream>>>(x, q, proj_w, proj_b,
          Whi + d*4096, Wlo + d*4096, Thi, Tlo, trigBh, trigBl,
          w_b + d*64, x, final_w, final_b, out);
    else if (d < DEPTH-1)
      k_combine<0,0><<<dim3(4,512), 256, 0, stream>>>(x, q, proj_w, proj_b,
          Whi + d*4096, Wlo + d*4096, Thi, Tlo, trigBh, trigBl,
          w_b + d*64, x, final_w, final_b, out);
    else
      k_combine<0,1><<<dim3(4,512), 256, 0, stream>>>(x, q, proj_w, proj_b,
          Whi + d*4096, Wlo + d*4096, Thi, Tlo, trigBh, trigBl,
          w_b + d*64, x, final_w, final_b, out);
  }
}